// Round 4
// baseline (333.252 us; speedup 1.0000x reference)
//
#include <hip/hip_runtime.h>
#include <cstdint>

// AdaptiveNet: x[16384,1024] -> fc1(4096)+sigmoid -> grouped(512 groups of 8)+sigmoid -> fc3(256)
// bf16 MFMA 16x16x32, BK=64, swizzled LDS (0 bank conflicts).
// R4: XCD-aware block scheduling for gemm1 — each XCD owns a 512-col slice of W1
// (1 MB, L2-resident) and sweeps M; x-tiles get their 4x N-reuse in L2.
// Theory: staging was L3-BW-bound (2.15 GB cache traffic @ ~9.6 TB/s = the 224 us wall).

#define B_ROWS 16384
#define DIN 1024
#define H1  4096
#define H2  512
#define DOUT 256
#define TILE 128
#define BK 64

#define NX4  (B_ROWS * DIN / 4)   // 4194304
#define NW14 (H1 * DIN / 4)       // 1048576
#define NW34 (DOUT * H2 / 4)      // 32768

typedef __bf16 bf16x8 __attribute__((ext_vector_type(8)));
typedef float f32x4 __attribute__((ext_vector_type(4)));

__device__ __forceinline__ unsigned short f2bf(float f) {
    union { float f; uint32_t u; } v; v.f = f;
    uint32_t u = v.u;
    u += 0x7FFFu + ((u >> 16) & 1u);   // round-to-nearest-even
    return (unsigned short)(u >> 16);
}

__device__ __forceinline__ float sigmoidf_fast(float x) {
    return 1.0f / (1.0f + __expf(-x));
}

// one launch converts x, W1, W3 fp32->bf16 (all ranges multiples of 256 threads)
__global__ __launch_bounds__(256) void cvt3_kernel(
    const float* __restrict__ x, const float* __restrict__ w1,
    const float* __restrict__ w3, unsigned short* __restrict__ xo,
    unsigned short* __restrict__ w1o, unsigned short* __restrict__ w3o) {
    int i = blockIdx.x * 256 + threadIdx.x;
    const float* src; unsigned short* dst; int j;
    if (i < NX4)              { src = x;  dst = xo;  j = i; }
    else if (i < NX4 + NW14)  { src = w1; dst = w1o; j = i - NX4; }
    else                      { src = w3; dst = w3o; j = i - NX4 - NW14; }
    float4 v = ((const float4*)src)[j];
    ushort4 o;
    o.x = f2bf(v.x); o.y = f2bf(v.y); o.z = f2bf(v.z); o.w = f2bf(v.w);
    ((ushort4*)dst)[j] = o;
}

__device__ __forceinline__ void load_lds16(const void* g, void* l) {
    __builtin_amdgcn_global_load_lds(
        (const __attribute__((address_space(1))) void*)g,
        (__attribute__((address_space(3))) void*)l, 16, 0, 0);
}

// Core K-loop, BK=64: C[128,128] tile, A row-major [M,K], B stored as [N,K], bf16.
// LDS row = 128B = 8 chunks of 16B, rotated by (r&7): fragment ds_read_b128 lands
// 2 lanes/bank (free), staging stays coalesced (8 lanes cover one 128B segment).
template <int K>
__device__ __forceinline__ void gemm_core(const unsigned short* __restrict__ A,
                                          const unsigned short* __restrict__ Bm,
                                          unsigned short* lsA, unsigned short* lsB,
                                          int a_row0, int b_row0,
                                          int lane, int wave, int wm, int wn,
                                          f32x4 acc[4][4]) {
    const int q = lane >> 4, m16 = lane & 15;

    // ---- staging addresses (loop-invariant): 4 chunks of 1KB per matrix per wave
    int gA[4], gB[4], lo[4];
#pragma unroll
    for (int i = 0; i < 4; ++i) {
        const int ch = wave * 4 + i;           // 0..15, chunk = 8 rows x 128B
        const int r  = ch * 8 + (lane >> 3);   // row this lane stages
        const int kc = ((lane & 7) - (lane >> 3)) & 7;  // swizzled k-chunk
        gA[i] = (a_row0 + r) * K + kc * 8;
        gB[i] = (b_row0 + r) * K + kc * 8;
        lo[i] = ch * 512;                      // elements (1KB); HW adds lane*16B
    }
    // ---- fragment-read offsets: slot s = (chunk + (row&7)) & 7, chunk = h*4+q
    int ra[2][4], rb[2][4];
#pragma unroll
    for (int h = 0; h < 2; ++h)
#pragma unroll
        for (int t = 0; t < 4; ++t) {
            const int s = ((h * 4 + q + (m16 & 7)) & 7) * 8;
            ra[h][t] = (wm + t * 16 + m16) * BK + s;
            rb[h][t] = (wn + t * 16 + m16) * BK + s;
        }

    for (int kt = 0; kt < K / BK; ++kt) {
        __syncthreads();                      // protect LDS from prior iter readers
        const int k0 = kt * BK;
#pragma unroll
        for (int i = 0; i < 4; ++i) {
            load_lds16(A + gA[i] + k0, lsA + lo[i]);
            load_lds16(Bm + gB[i] + k0, lsB + lo[i]);
        }
        __syncthreads();                      // staged (syncthreads drains vmcnt)
#pragma unroll
        for (int h = 0; h < 2; ++h) {
            bf16x8 af[4], bfr[4];
#pragma unroll
            for (int t = 0; t < 4; ++t) af[t]  = *(const bf16x8*)(lsA + ra[h][t]);
#pragma unroll
            for (int t = 0; t < 4; ++t) bfr[t] = *(const bf16x8*)(lsB + rb[h][t]);
#pragma unroll
            for (int r = 0; r < 4; ++r)
#pragma unroll
                for (int c = 0; c < 4; ++c)
                    acc[r][c] = __builtin_amdgcn_mfma_f32_16x16x32_bf16(
                        af[r], bfr[c], acc[r][c], 0, 0, 0);
        }
    }
}

// GEMM1: h = sigmoid(x @ W1^T + b1); fused layer2: x2 = sigmoid(groupdot(h,W2)+b2)
// 1-D grid of 4096 blocks; XCD-aware decode:
//   xcd = bid&7 owns W1 columns [xcd*512, xcd*512+512)  (1 MB, L2-resident)
//   local = bid>>3: n_local = local&3, m_tile = local>>2  (4 N-tiles of same M
//   are consecutive -> x-tile 4x reuse hits L2)
__global__ __launch_bounds__(256, 2) void gemm1_fused(
    const unsigned short* __restrict__ Xb,   // [16384,1024] bf16
    const unsigned short* __restrict__ W1b,  // [4096,1024]  bf16 (N,K)
    const float* __restrict__ b1,            // [4096]
    const float* __restrict__ W2,            // [512*8] flat; W2[g][s] = W2[gn]
    const float* __restrict__ b2,            // [512]
    unsigned short* __restrict__ X2) {       // [16384,512] bf16
    __shared__ __attribute__((aligned(16))) unsigned short lsA[TILE * BK];
    __shared__ __attribute__((aligned(16))) unsigned short lsB[TILE * BK];
    const int tid = threadIdx.x, lane = tid & 63, wave = tid >> 6;
    const int wm = (wave >> 1) * 64, wn = (wave & 1) * 64;

    const int bid = blockIdx.x;
    const int xcd = bid & 7;
    const int local = bid >> 3;
    const int n0 = (xcd * 4 + (local & 3)) * TILE;
    const int a0 = (local >> 2) * TILE;

    f32x4 acc[4][4];
#pragma unroll
    for (int r = 0; r < 4; ++r)
#pragma unroll
        for (int c = 0; c < 4; ++c) acc[r][c] = (f32x4)0.0f;

    gemm_core<DIN>(Xb, W1b, lsA, lsB, a0, n0, lane, wave, wm, wn, acc);

    // Epilogue. C/D layout (m89): col = lane&15, row = (lane>>4)*4 + reg.
    const int q = lane >> 4, m16 = lane & 15;
#pragma unroll
    for (int c = 0; c < 4; ++c) {
        const int gn = n0 + wn + c * 16 + m16;        // h column
        const float w2v = W2[gn];                     // gn == g*8 + s
        const float b1v = b1[gn];
        const int g = gn >> 3;
        const float b2v = b2[g];
#pragma unroll
        for (int r = 0; r < 4; ++r) {
#pragma unroll
            for (int i = 0; i < 4; ++i) {
                const int gm = a0 + wm + r * 16 + q * 4 + i;
                float h = sigmoidf_fast(acc[r][c][i] + b1v);
                float v = h * w2v;
                // group of 8 consecutive columns == 8 adjacent lanes
                v += __shfl_xor(v, 1, 64);
                v += __shfl_xor(v, 2, 64);
                v += __shfl_xor(v, 4, 64);
                if ((lane & 7) == 0)
                    X2[gm * H2 + g] = f2bf(sigmoidf_fast(v + b2v));
            }
        }
    }
}

// GEMM3: out = x2 @ W3^T + b3, fp32 out [16384, 256]
__global__ __launch_bounds__(256, 2) void gemm3_kernel(
    const unsigned short* __restrict__ X2,   // [16384,512] bf16
    const unsigned short* __restrict__ W3b,  // [256,512] bf16 (N,K)
    const float* __restrict__ b3,            // [256]
    float* __restrict__ Out) {               // [16384,256] f32
    __shared__ __attribute__((aligned(16))) unsigned short lsA[TILE * BK];
    __shared__ __attribute__((aligned(16))) unsigned short lsB[TILE * BK];
    const int tid = threadIdx.x, lane = tid & 63, wave = tid >> 6;
    const int wm = (wave >> 1) * 64, wn = (wave & 1) * 64;
    const int a0 = blockIdx.y * TILE;
    const int n0 = blockIdx.x * TILE;

    f32x4 acc[4][4];
#pragma unroll
    for (int r = 0; r < 4; ++r)
#pragma unroll
        for (int c = 0; c < 4; ++c) acc[r][c] = (f32x4)0.0f;

    gemm_core<H2>(X2, W3b, lsA, lsB, a0, n0, lane, wave, wm, wn, acc);

    const int q = lane >> 4, m16 = lane & 15;
#pragma unroll
    for (int c = 0; c < 4; ++c) {
        const int gn = n0 + wn + c * 16 + m16;
        const float b3v = b3[gn];
#pragma unroll
        for (int r = 0; r < 4; ++r) {
#pragma unroll
            for (int i = 0; i < 4; ++i) {
                const int gm = a0 + wm + r * 16 + q * 4 + i;
                Out[gm * DOUT + gn] = acc[r][c][i] + b3v;
            }
        }
    }
}

extern "C" void kernel_launch(void* const* d_in, const int* in_sizes, int n_in,
                              void* d_out, int out_size, void* d_ws, size_t ws_size,
                              hipStream_t stream) {
    const float* x  = (const float*)d_in[0];
    const float* W1 = (const float*)d_in[1];
    const float* b1 = (const float*)d_in[2];
    const float* W2 = (const float*)d_in[3];
    const float* b2 = (const float*)d_in[4];
    const float* W3 = (const float*)d_in[5];
    const float* b3 = (const float*)d_in[6];
    float* out = (float*)d_out;

    char* ws = (char*)d_ws;
    unsigned short* x_bf  = (unsigned short*)ws;                         // 33,554,432 B
    unsigned short* w1_bf = (unsigned short*)(ws + 33554432);            //  8,388,608 B
    unsigned short* w3_bf = (unsigned short*)(ws + 33554432 + 8388608);  //    262,144 B
    unsigned short* x2_bf = (unsigned short*)(ws + 33554432 + 8388608 + 262144); // 16,777,216 B

    // one launch for all fp32->bf16 conversions
    cvt3_kernel<<<(NX4 + NW14 + NW34) / 256, 256, 0, stream>>>(
        x, W1, W3, x_bf, w1_bf, w3_bf);

    // GEMM1 + fused layer 2: 1-D grid, XCD-aware decode inside
    gemm1_fused<<<(B_ROWS / TILE) * (H1 / TILE), 256, 0, stream>>>(
        x_bf, w1_bf, b1, W2, b2, x2_bf);

    // GEMM3: grid = (2, 128)
    gemm3_kernel<<<dim3(DOUT / TILE, B_ROWS / TILE), 256, 0, stream>>>(
        x2_bf, w3_bf, b3, out);
}

// Round 5
// 274.491 us; speedup vs baseline: 1.2141x; 1.2141x over previous
//
#include <hip/hip_runtime.h>
#include <cstdint>

// AdaptiveNet: x[16384,1024] -> fc1(4096)+sigmoid -> grouped(512 g of 8)+sigmoid -> fc3(256)
// R5: GEMM1 in fp8-e4m3 (W1 pre-scaled x64, acc/64 in epilogue). BK=128 in 32KB LDS:
// half the barriers, half the staged bytes, same MFMA count. gemm3 stays bf16.

#define B_ROWS 16384
#define DIN 1024
#define H1  4096
#define H2  512
#define DOUT 256
#define TILE 128
#define BK 64          // bf16 core (gemm3)
#define BK1 128        // fp8 core (gemm1)
#define INV_W1SCALE 0.015625f   // 1/64

#define NX4  (B_ROWS * DIN / 4)   // 4194304
#define NW14 (H1 * DIN / 4)       // 1048576
#define NW34 (DOUT * H2 / 4)      // 32768

typedef __bf16 bf16x8 __attribute__((ext_vector_type(8)));
typedef float f32x4 __attribute__((ext_vector_type(4)));

__device__ __forceinline__ unsigned short f2bf(float f) {
    union { float f; uint32_t u; } v; v.f = f;
    uint32_t u = v.u;
    u += 0x7FFFu + ((u >> 16) & 1u);   // round-to-nearest-even
    return (unsigned short)(u >> 16);
}

__device__ __forceinline__ float sigmoidf_fast(float x) {
    return 1.0f / (1.0f + __expf(-x));
}

// x -> fp8 (x1), W1 -> fp8 (x64), W3 -> bf16, one launch
__global__ __launch_bounds__(256) void cvt3_kernel(
    const float* __restrict__ x, const float* __restrict__ w1,
    const float* __restrict__ w3, unsigned int* __restrict__ xo,
    unsigned int* __restrict__ w1o, unsigned short* __restrict__ w3o) {
    int i = blockIdx.x * 256 + threadIdx.x;
    if (i < NX4) {
        float4 v = ((const float4*)x)[i];
        unsigned int p = 0;
        p = __builtin_amdgcn_cvt_pk_fp8_f32(v.x, v.y, p, false);
        p = __builtin_amdgcn_cvt_pk_fp8_f32(v.z, v.w, p, true);
        xo[i] = p;
    } else if (i < NX4 + NW14) {
        int j = i - NX4;
        float4 v = ((const float4*)w1)[j];
        unsigned int p = 0;
        p = __builtin_amdgcn_cvt_pk_fp8_f32(v.x * 64.0f, v.y * 64.0f, p, false);
        p = __builtin_amdgcn_cvt_pk_fp8_f32(v.z * 64.0f, v.w * 64.0f, p, true);
        w1o[j] = p;
    } else {
        int j = i - NX4 - NW14;
        float4 v = ((const float4*)w3)[j];
        ushort4 o;
        o.x = f2bf(v.x); o.y = f2bf(v.y); o.z = f2bf(v.z); o.w = f2bf(v.w);
        ((ushort4*)w3o)[j] = o;
    }
}

__device__ __forceinline__ void load_lds16(const void* g, void* l) {
    __builtin_amdgcn_global_load_lds(
        (const __attribute__((address_space(1))) void*)g,
        (__attribute__((address_space(3))) void*)l, 16, 0, 0);
}

// ---------------- fp8 core, BK1=128, tile 128x128 ----------------
// LDS row = 128 fp8 = 128B = 8 chunks of 16B, chunk slots rotated by (row&7).
// Staging identical byte-geometry to the bf16/BK64 core (verified conflict-free).
// A-frag (16x16x32 fp8): lane(q=l>>4,m=l&15) holds 8 consecutive fp8 at k=q*8
// within each k32 sub-chunk s; byte addr = row*128 + slot(2s+(q>>1))*16 + (q&1)*8.
__global__ __launch_bounds__(256, 2) void gemm1_fused(
    const unsigned char* __restrict__ Xq,    // [16384,1024] fp8
    const unsigned char* __restrict__ W1q,   // [4096,1024]  fp8 (N,K), x64
    const float* __restrict__ b1,            // [4096]
    const float* __restrict__ W2,            // [512*8] flat; W2[g][s] = W2[gn]
    const float* __restrict__ b2,            // [512]
    unsigned short* __restrict__ X2) {       // [16384,512] bf16
    __shared__ __attribute__((aligned(16))) unsigned char lsA[TILE * BK1];
    __shared__ __attribute__((aligned(16))) unsigned char lsB[TILE * BK1];
    const int tid = threadIdx.x, lane = tid & 63, wave = tid >> 6;
    const int wm = (wave >> 1) * 64, wn = (wave & 1) * 64;

    // XCD-aware decode (R4): xcd owns a 512-col W1 slice (L2-resident)
    const int bid = blockIdx.x;
    const int xcd = bid & 7;
    const int local = bid >> 3;
    const int n0 = (xcd * 4 + (local & 3)) * TILE;
    const int a0 = (local >> 2) * TILE;

    const int q = lane >> 4, m16 = lane & 15;

    // staging: 4 chunks of 1KB per matrix per wave; chunk = 8 rows x 128B
    int gA[4], gB[4], lo[4];
#pragma unroll
    for (int i = 0; i < 4; ++i) {
        const int ch = wave * 4 + i;
        const int r  = ch * 8 + (lane >> 3);
        const int kc = ((lane & 7) - (lane >> 3)) & 7;
        gA[i] = (a0 + r) * DIN + kc * 16;
        gB[i] = (n0 + r) * DIN + kc * 16;
        lo[i] = ch * 1024;
    }
    // fragment offsets: rowbase (t) + slotoff (s)
    int rowA[4], rowB[4], so[4];
#pragma unroll
    for (int t = 0; t < 4; ++t) {
        rowA[t] = (wm + t * 16 + m16) * BK1 + (q & 1) * 8;
        rowB[t] = (wn + t * 16 + m16) * BK1 + (q & 1) * 8;
    }
#pragma unroll
    for (int s = 0; s < 4; ++s)
        so[s] = ((s * 2 + (q >> 1) + (m16 & 7)) & 7) * 16;

    f32x4 acc[4][4];
#pragma unroll
    for (int r = 0; r < 4; ++r)
#pragma unroll
        for (int c = 0; c < 4; ++c) acc[r][c] = (f32x4)0.0f;

    for (int kt = 0; kt < DIN / BK1; ++kt) {
        __syncthreads();
        const int k0 = kt * BK1;
#pragma unroll
        for (int i = 0; i < 4; ++i) {
            load_lds16(Xq + gA[i] + k0, lsA + lo[i]);
            load_lds16(W1q + gB[i] + k0, lsB + lo[i]);
        }
        __syncthreads();
#pragma unroll
        for (int s = 0; s < 4; ++s) {
            long af[4], bfr[4];
#pragma unroll
            for (int t = 0; t < 4; ++t) af[t]  = *(const long*)(lsA + rowA[t] + so[s]);
#pragma unroll
            for (int t = 0; t < 4; ++t) bfr[t] = *(const long*)(lsB + rowB[t] + so[s]);
#pragma unroll
            for (int r = 0; r < 4; ++r)
#pragma unroll
                for (int c = 0; c < 4; ++c)
                    acc[r][c] = __builtin_amdgcn_mfma_f32_16x16x32_fp8_fp8(
                        af[r], bfr[c], acc[r][c], 0, 0, 0);
        }
    }

    // Epilogue. C/D layout: col = lane&15, row = (lane>>4)*4 + reg. acc is 64x true z1.
#pragma unroll
    for (int c = 0; c < 4; ++c) {
        const int gn = n0 + wn + c * 16 + m16;        // h column
        const float w2v = W2[gn];
        const float b1v = b1[gn];
        const int g = gn >> 3;
        const float b2v = b2[g];
#pragma unroll
        for (int r = 0; r < 4; ++r) {
#pragma unroll
            for (int i = 0; i < 4; ++i) {
                const int gm = a0 + wm + r * 16 + q * 4 + i;
                float h = sigmoidf_fast(acc[r][c][i] * INV_W1SCALE + b1v);
                float v = h * w2v;
                v += __shfl_xor(v, 1, 64);
                v += __shfl_xor(v, 2, 64);
                v += __shfl_xor(v, 4, 64);
                if ((lane & 7) == 0)
                    X2[gm * H2 + g] = f2bf(sigmoidf_fast(v + b2v));
            }
        }
    }
}

// ---------------- bf16 core, BK=64 (gemm3) ----------------
template <int K>
__device__ __forceinline__ void gemm_core(const unsigned short* __restrict__ A,
                                          const unsigned short* __restrict__ Bm,
                                          unsigned short* lsA, unsigned short* lsB,
                                          int a_row0, int b_row0,
                                          int lane, int wave, int wm, int wn,
                                          f32x4 acc[4][4]) {
    const int q = lane >> 4, m16 = lane & 15;
    int gA[4], gB[4], lo[4];
#pragma unroll
    for (int i = 0; i < 4; ++i) {
        const int ch = wave * 4 + i;
        const int r  = ch * 8 + (lane >> 3);
        const int kc = ((lane & 7) - (lane >> 3)) & 7;
        gA[i] = (a_row0 + r) * K + kc * 8;
        gB[i] = (b_row0 + r) * K + kc * 8;
        lo[i] = ch * 512;
    }
    int ra[2][4], rb[2][4];
#pragma unroll
    for (int h = 0; h < 2; ++h)
#pragma unroll
        for (int t = 0; t < 4; ++t) {
            const int s = ((h * 4 + q + (m16 & 7)) & 7) * 8;
            ra[h][t] = (wm + t * 16 + m16) * BK + s;
            rb[h][t] = (wn + t * 16 + m16) * BK + s;
        }
    for (int kt = 0; kt < K / BK; ++kt) {
        __syncthreads();
        const int k0 = kt * BK;
#pragma unroll
        for (int i = 0; i < 4; ++i) {
            load_lds16(A + gA[i] + k0, lsA + lo[i]);
            load_lds16(Bm + gB[i] + k0, lsB + lo[i]);
        }
        __syncthreads();
#pragma unroll
        for (int h = 0; h < 2; ++h) {
            bf16x8 af[4], bfr[4];
#pragma unroll
            for (int t = 0; t < 4; ++t) af[t]  = *(const bf16x8*)(lsA + ra[h][t]);
#pragma unroll
            for (int t = 0; t < 4; ++t) bfr[t] = *(const bf16x8*)(lsB + rb[h][t]);
#pragma unroll
            for (int r = 0; r < 4; ++r)
#pragma unroll
                for (int c = 0; c < 4; ++c)
                    acc[r][c] = __builtin_amdgcn_mfma_f32_16x16x32_bf16(
                        af[r], bfr[c], acc[r][c], 0, 0, 0);
        }
    }
}

__global__ __launch_bounds__(256, 2) void gemm3_kernel(
    const unsigned short* __restrict__ X2,   // [16384,512] bf16
    const unsigned short* __restrict__ W3b,  // [256,512] bf16 (N,K)
    const float* __restrict__ b3,            // [256]
    float* __restrict__ Out) {               // [16384,256] f32
    __shared__ __attribute__((aligned(16))) unsigned short lsA[TILE * BK];
    __shared__ __attribute__((aligned(16))) unsigned short lsB[TILE * BK];
    const int tid = threadIdx.x, lane = tid & 63, wave = tid >> 6;
    const int wm = (wave >> 1) * 64, wn = (wave & 1) * 64;
    const int a0 = blockIdx.y * TILE;
    const int n0 = blockIdx.x * TILE;

    f32x4 acc[4][4];
#pragma unroll
    for (int r = 0; r < 4; ++r)
#pragma unroll
        for (int c = 0; c < 4; ++c) acc[r][c] = (f32x4)0.0f;

    gemm_core<H2>(X2, W3b, lsA, lsB, a0, n0, lane, wave, wm, wn, acc);

    const int q = lane >> 4, m16 = lane & 15;
#pragma unroll
    for (int c = 0; c < 4; ++c) {
        const int gn = n0 + wn + c * 16 + m16;
        const float b3v = b3[gn];
#pragma unroll
        for (int r = 0; r < 4; ++r) {
#pragma unroll
            for (int i = 0; i < 4; ++i) {
                const int gm = a0 + wm + r * 16 + q * 4 + i;
                Out[gm * DOUT + gn] = acc[r][c][i] + b3v;
            }
        }
    }
}

extern "C" void kernel_launch(void* const* d_in, const int* in_sizes, int n_in,
                              void* d_out, int out_size, void* d_ws, size_t ws_size,
                              hipStream_t stream) {
    const float* x  = (const float*)d_in[0];
    const float* W1 = (const float*)d_in[1];
    const float* b1 = (const float*)d_in[2];
    const float* W2 = (const float*)d_in[3];
    const float* b2 = (const float*)d_in[4];
    const float* W3 = (const float*)d_in[5];
    const float* b3 = (const float*)d_in[6];
    float* out = (float*)d_out;

    char* ws = (char*)d_ws;
    unsigned char*  x_q   = (unsigned char*)ws;                          // 16,777,216 B
    unsigned char*  w1_q  = (unsigned char*)(ws + 16777216);             //  4,194,304 B
    unsigned short* w3_bf = (unsigned short*)(ws + 16777216 + 4194304);  //    262,144 B
    unsigned short* x2_bf = (unsigned short*)(ws + 16777216 + 4194304 + 262144); // 16,777,216 B

    cvt3_kernel<<<(NX4 + NW14 + NW34) / 256, 256, 0, stream>>>(
        x, W1, W3, (unsigned int*)x_q, (unsigned int*)w1_q, w3_bf);

    // GEMM1 (fp8) + fused layer 2: 1-D grid, XCD-aware decode inside
    gemm1_fused<<<(B_ROWS / TILE) * (H1 / TILE), 256, 0, stream>>>(
        x_q, w1_q, b1, W2, b2, x2_bf);

    // GEMM3 (bf16): grid = (2, 128)
    gemm3_kernel<<<dim3(DOUT / TILE, B_ROWS / TILE), 256, 0, stream>>>(
        x2_bf, w3_bf, b3, out);
}